// Round 4
// baseline (104.697 us; speedup 1.0000x reference)
//
#include <hip/hip_runtime.h>
#include <hip/hip_fp16.h>

// DeformConv2d: B=16, Cin=64, Cout=64, H=W=64, K=3, stride=1, pad=1, dil=1
// Round 20: VALU-trim on R19's halo structure (structure/LDS ops unchanged).
// Pipe model: VALU ~19us/CU and LDS ~17us/CU are co-dominant; this round cuts
// ~115 VALU/thread: (a) stage loop incremental hx/hy (no div/mod-37),
// (b) phase A ch=1 frag addr = ch=0 addr ^ 32 (slot XOR-4), tap-outer loop,
// (c) phase B hoisted cols bases + ^32 trick + early weight prefetch.
// All addresses/values/orders identical -> bit-identical output vs R19.

#define KOFF 18
#define HROWS 5
#define HCOLS 37
#define HALO_HALFS (HROWS * HCOLS * 64)   // 11840 halfs = 23680 B
#define CS3 192                            // cols chunk stride (3 taps)

#define W2T_HALFS    (18 * 64 * 32)     // [i][64co][32kl], k' = tap*64+cin
#define WOFF2T_HALFS (18 * 32 * 32)     // [i][32co][32kl]
#define W2T_BYTES    (W2T_HALFS * 2)    // 73728
#define WOFF2T_OFF   W2T_BYTES
#define X_OFF        (W2T_BYTES + WOFF2T_HALFS * 2)   // 110592 (16B aligned)
#define XH_BYTES     (16 * 64 * 64 * 64 * 2)          // 8388608
#define WS_NEED      (X_OFF + XH_BYTES)               // 8499200

typedef _Float16 half8 __attribute__((ext_vector_type(8)));
typedef float floatx4 __attribute__((ext_vector_type(4)));

union H8 { half8 v; __half2 h2[4]; uint4 u; };

// ---------------------------------------------------------------------------
// prep: blocks [0,1024): LDS-tiled transpose of one (b,y) plane (coalesced
// both sides). blocks [1024,1240): weight repack (tap-major f16).
__global__ void prep(const float* __restrict__ x,
                     const float* __restrict__ w_dcn,
                     const float* __restrict__ w_off,
                     _Float16* __restrict__ w2t,
                     _Float16* __restrict__ woff2t,
                     _Float16* __restrict__ xh) {
    const int bi = blockIdx.x;
    const int t  = threadIdx.x;
    if (bi < 1024) {
        const int b = bi >> 6, y = bi & 63;
        __shared__ __align__(16) _Float16 tile[64 * 72];
        const int xx = t & 63;
        const int c4 = t >> 6;
        const float* xp = x + (((size_t)b * 64) * 64 + y) * 64;
#pragma unroll
        for (int p = 0; p < 16; ++p) {
            int cin = p * 4 + c4;
            tile[xx * 72 + cin] = (_Float16)xp[(size_t)cin * 4096 + xx];
        }
        __syncthreads();
        const int oct = t & 7;
        const int xl  = t >> 3;
        _Float16* op = xh + ((((size_t)b * 64 + y) * 64) << 6);
#pragma unroll
        for (int p = 0; p < 2; ++p) {
            int xr = p * 32 + xl;
            half8 v = *(const half8*)&tile[xr * 72 + oct * 8];
            *(half8*)&op[(size_t)xr * 64 + oct * 8] = v;
        }
    } else {
        int e = (bi - 1024) * 256 + t;
        if (e < W2T_HALFS) {
            int kl = e & 31, co = (e >> 5) & 63, i = e >> 11;
            int tap = i >> 1, cin = (i & 1) * 32 + kl;
            w2t[e] = (_Float16)w_dcn[co * 576 + cin * 9 + tap];
        } else {
            int e2 = e - W2T_HALFS;
            int kl = e2 & 31, co = (e2 >> 5) & 31, i = e2 >> 10;
            int tap = i >> 1, cin = (i & 1) * 32 + kl;
            woff2t[e2] = (co < KOFF) ? (_Float16)w_off[co * 576 + cin * 9 + tap]
                                     : (_Float16)0.f;
        }
    }
}

// ---------------------------------------------------------------------------
// dcn_one: halo-staged offset conv + geometry + gather + GEMM in one kernel.
__launch_bounds__(256, 4)
__global__ void dcn_one(const _Float16* __restrict__ xh,
                        const _Float16* __restrict__ w2t,
                        const _Float16* __restrict__ woff2t,
                        const float* __restrict__ b_off,
                        const float* __restrict__ b_dcn,
                        float* __restrict__ out) {
    const int bid = blockIdx.x;                 // 0..2047
    const int s   = bid >> 3;
    const int b   = ((bid & 7) << 1) | (s >> 7);
    const int ho  = (s >> 1) & 63;
    const int hlf = s & 1;
    const int t    = threadIdx.x;
    const int lane = t & 63;
    const int wid  = __builtin_amdgcn_readfirstlane(t >> 6);
    const int r    = lane & 15;
    const int q    = lane >> 4;
    const int gpx  = t >> 3;                    // 0..31 gather pixel
    const int oct  = t & 7;                     // 8-cin octet
    const int pxg  = hlf * 32;

    // LDS: halo 23680 + cols 12288 + meta 1152 + weights 2304 = 39424 B
    __shared__ __align__(16) _Float16 haloL[HALO_HALFS];
    __shared__ __align__(16) _Float16 colsL[32 * CS3];
    __shared__ __align__(16) unsigned int gmetaL[288];
    __shared__ __align__(16) uint2        gwL[288];
    float* offlds = (float*)colsL;              // overlay: used before cols

    const _Float16* xb = xh + ((size_t)b << 18);
    const char* xpb = (const char*)xb;

    // ---- 1. stage halo: rows ho-2..ho+2, cols pxg-2..pxg+34, swizzled ----
    // 16B slot s at (hy,hx) holds cin-octet (s ^ (hx&7)); OOB zero-filled.
    // Incremental (hy,hx) indexing: no div/mod in the loop.
    {
        const int sl = t & 7;
        int rest = t >> 3;                      // hy*37 + hx
        int hx = rest;                          // rest<=31 < 37 -> hy=0
        int hy = 0;
#pragma unroll
        for (int it = 0; it < 6; ++it) {
            if (rest < HROWS * HCOLS) {
                int y  = ho - 2 + hy;
                int xx = pxg - 2 + hx;
                half8 v = {};
                if (((unsigned)y < 64u) && ((unsigned)xx < 64u)) {
                    int oc = sl ^ (hx & 7);
                    v = *(const half8*)&xb[(((size_t)(y * 64 + xx)) << 6) + oc * 8];
                }
                *(half8*)&haloL[(size_t)(rest * 8 + sl) * 8] = v;
            }
            rest += 32;
            hx += 32;
            if (hx >= HCOLS) { hx -= HCOLS; hy += 1; }
        }
    }
    __syncthreads();

    // ---- 2. phase A: offset conv, B-frags straight from halo -------------
    {
        floatx4 am = {0.f, 0.f, 0.f, 0.f};
        const int m = wid & 1, n = wid >> 1;
        const int px_ = n * 16 + r;
        const int wbase = (m * 16 + r) * 32 + q * 8;
#pragma unroll
        for (int tap = 0; tap < 9; ++tap) {
            const int hy  = tap / 3 + 1;                // compile-time (unrolled)
            const int hxA = px_ + (tap % 3) + 1;
            const int sl0 = q ^ (hxA & 7);
            const int bidx = ((hy * HCOLS + hxA) * 8 + sl0) * 8;
            half8 bf0 = *(const half8*)&haloL[bidx];
            half8 a0  = *(const half8*)&woff2t[(2 * tap) * 1024 + wbase];
            am = __builtin_amdgcn_mfma_f32_16x16x32_f16(a0, bf0, am, 0, 0, 0);
            half8 bf1 = *(const half8*)&haloL[bidx ^ 32];   // slot ^4 == byte ^64
            half8 a1  = *(const half8*)&woff2t[(2 * tap + 1) * 1024 + wbase];
            am = __builtin_amdgcn_mfma_f32_16x16x32_f16(a1, bf1, am, 0, 0, 0);
        }
#pragma unroll
        for (int reg = 0; reg < 4; ++reg) {
            int co = m * 16 + q * 4 + reg;
            if (co < KOFF)
                offlds[co * 32 + n * 16 + r] = am[reg] + b_off[co];
        }
    }
    __syncthreads();

    // ---- 3. geometry records (identical weight arithmetic) ---------------
    for (int e = t; e < 9 * 32; e += 256) {
        int tap = e >> 5, px = e & 31;
        float offy = offlds[(2 * tap) * 32 + px];
        float offx = offlds[(2 * tap + 1) * 32 + px];
        float py  = offy + (float)(tap / 3) + (float)(ho - 1);
        float pxf = offx + (float)(tap % 3) + (float)(pxg + px - 1);
        float fy = floorf(py), fx = floorf(pxf);
        int y0 = (int)fy, x0 = (int)fx;
        float wy1 = py - fy, wx1 = pxf - fx;
        float wy0 = 1.f - wy1, wx0 = 1.f - wx1;
        bool y0ok = ((unsigned)y0 < 64u);
        bool x0ok = ((unsigned)x0 < 64u);
        bool y1ok = ((unsigned)(y0 + 1) < 64u);
        bool x1ok = ((unsigned)(x0 + 1) < 64u);
        float w00 = (y0ok && x0ok) ? wy0 * wx0 : 0.f;
        float w01 = (y0ok && x1ok) ? wy0 * wx1 : 0.f;
        float w10 = (y1ok && x0ok) ? wy1 * wx0 : 0.f;
        float w11 = (y1ok && x1ok) ? wy1 * wx1 : 0.f;
        int yc0 = min(max(y0, 0), 63);
        int xc0 = min(max(x0, 0), 63);
        int yc1 = min(max(y0 + 1, 0), 63);
        int xc1 = min(max(x0 + 1, 0), 63);
        union { __half2 h; unsigned u; } c0, c1;
        c0.h = __floats2half2_rn(w00, w01);
        c1.h = __floats2half2_rn(w10, w11);
        // fast path iff all (clamped) corners live inside the staged halo box
        bool fast = (yc0 >= ho - 2) && (yc1 <= ho + 2)
                 && (xc0 >= pxg - 2) && (xc1 <= pxg + 34);
        unsigned meta;
        if (fast) {
            unsigned hy0 = (unsigned)(yc0 - (ho - 2));
            unsigned hx0 = (unsigned)(xc0 - (pxg - 2));
            meta = 0x80000000u | hx0 | (hy0 << 8)
                 | ((unsigned)(xc1 - xc0) << 16)
                 | ((unsigned)(yc1 - yc0) << 17);
        } else {
            meta = (unsigned)(yc0 * 64 + xc0)
                 | ((unsigned)(xc1 - xc0) << 12)
                 | ((unsigned)(yc1 - yc0) << 13);
        }
        gmetaL[e] = meta;
        gwL[e]    = make_uint2(c0.u, c1.u);
    }
    __syncthreads();

    // ---- 4. phase B: 3 chunks of 3 taps; gather from halo LDS ------------
    floatx4 acc0 = {0.f, 0.f, 0.f, 0.f};
    floatx4 acc1 = {0.f, 0.f, 0.f, 0.f};

    // hoisted LDS index bases (halfs)
    const int colsWidx = gpx * CS3 + (oct ^ (gpx & 7)) * 8;     // gather write
    const int rdA = r * CS3 + (q ^ (r & 7)) * 8;                // MFMA b0 read
    const int rdB = (16 + r) * CS3 + (q ^ (r & 7)) * 8;         // MFMA b1 read
    const int wb2 = (wid * 16 + r) * 32 + q * 8;                // w2t lane base

#pragma unroll
    for (int c = 0; c < 3; ++c) {
        // weight prefetch first: in flight across the whole gather phase
        half8 wf6[6];
#pragma unroll
        for (int u = 0; u < 6; ++u)
            wf6[u] = *(const half8*)&w2t[(size_t)(c * 6 + u) * 2048 + wb2];

        // gather + combine 3 taps for pixel gpx, octet oct
#pragma unroll
        for (int u3 = 0; u3 < 3; ++u3) {
            const int tap = c * 3 + u3;
            unsigned meta = gmetaL[tap * 32 + gpx];
            uint2    wr   = gwL[tap * 32 + gpx];
            H8 v00, v01, v10, v11;
            if (meta & 0x80000000u) {
                int hx0 = (int)(meta & 63u);
                int hy0 = (int)((meta >> 8) & 7u);
                int dx  = (int)((meta >> 16) & 1u);
                int dy  = (int)((meta >> 17) & 1u);
                int b0i = hy0 * HCOLS + hx0;
                int s0  = oct ^ (hx0 & 7);
                int s1  = oct ^ ((hx0 + dx) & 7);
                v00.v = *(const half8*)&haloL[(b0i * 8 + s0) * 8];
                v01.v = *(const half8*)&haloL[((b0i + dx) * 8 + s1) * 8];
                v10.v = *(const half8*)&haloL[((b0i + dy * HCOLS) * 8 + s0) * 8];
                v11.v = *(const half8*)&haloL[((b0i + dy * HCOLS + dx) * 8 + s1) * 8];
            } else {
                unsigned a00 = (meta & 0xfffu) * 128u + (unsigned)oct * 16u;
                unsigned dx128  = ((meta >> 12) & 1u) * 128u;
                unsigned dy8192 = ((meta >> 13) & 1u) * 8192u;
                v00.v = *(const half8*)(xpb + a00);
                v01.v = *(const half8*)(xpb + a00 + dx128);
                v10.v = *(const half8*)(xpb + a00 + dy8192);
                v11.v = *(const half8*)(xpb + a00 + dy8192 + dx128);
            }
            union { unsigned u; __half2 h; } cy, cz;
            cy.u = wr.x;
            cz.u = wr.y;
            __half2 W00 = __half2half2(__low2half(cy.h));
            __half2 W01 = __half2half2(__high2half(cy.h));
            __half2 W10 = __half2half2(__low2half(cz.h));
            __half2 W11 = __half2half2(__high2half(cz.h));
            H8 res;
#pragma unroll
            for (int cc = 0; cc < 4; ++cc) {
                __half2 aa = __hmul2(v00.h2[cc], W00);
                aa = __hfma2(v01.h2[cc], W01, aa);
                aa = __hfma2(v10.h2[cc], W10, aa);
                aa = __hfma2(v11.h2[cc], W11, aa);
                res.h2[cc] = aa;
            }
            *(half8*)&colsL[colsWidx + u3 * 64] = res.v;
        }
        __syncthreads();
#pragma unroll
        for (int u = 0; u < 6; ++u) {
            const int u3 = u >> 1;
            const int x32 = (u & 1) * 32;              // ch=1: slot^4 == idx^32
            half8 b0 = *(const half8*)&colsL[(rdA + u3 * 64) ^ x32];
            half8 b1 = *(const half8*)&colsL[(rdB + u3 * 64) ^ x32];
            acc0 = __builtin_amdgcn_mfma_f32_16x16x32_f16(wf6[u], b0, acc0, 0, 0, 0);
            acc1 = __builtin_amdgcn_mfma_f32_16x16x32_f16(wf6[u], b1, acc1, 0, 0, 0);
        }
        if (c < 2) __syncthreads();
    }

    // ---- epilogue --------------------------------------------------------
#pragma unroll
    for (int reg = 0; reg < 4; ++reg) {
        int co = wid * 16 + q * 4 + reg;
        float bias = b_dcn[co];
        size_t o = (((size_t)b * 64 + co) * 64 + ho) * 64 + pxg;
        out[o + r]      = acc0[reg] + bias;
        out[o + 16 + r] = acc1[reg] + bias;
    }
}

// ---------------------------------------------------------------------------
// Fallback (R11-proven, x f32 direct) used only if ws too small.
#define FCPAD 40
__launch_bounds__(256, 4)
__global__ void dcn_fb(const float* __restrict__ x,
                       const float* __restrict__ w_dcn,
                       const float* __restrict__ w_off,
                       const float* __restrict__ b_off,
                       const float* __restrict__ b_dcn,
                       float* __restrict__ out) {
    const int bid = blockIdx.x;
    const int s   = bid >> 3;
    const int b   = ((bid & 7) << 1) | (s >> 7);
    const int ho  = (s >> 1) & 63;
    const int hlf = s & 1;
    const int t    = threadIdx.x;
    const int lane = t & 63;
    const int wid  = __builtin_amdgcn_readfirstlane(t >> 6);
    const int r    = lane & 15;
    const int q    = lane >> 4;
    const int px   = t & 31;
    const int kq   = t >> 5;

    __shared__ __align__(16) _Float16 colsT[2][32 * FCPAD];
    __shared__ __align__(16) float    offlds[KOFF * 32];

    const float* xb = x + (size_t)b * 64 * 4096;
    const int pxg = hlf * 32;

    {
        floatx4 am = {0.f, 0.f, 0.f, 0.f};
        const int m = wid & 1, n = wid >> 1;
        auto stageA = [&](int i) {
            const int tap = i >> 1;
            const int dy = tap / 3, dxk = tap - dy * 3;
            const int y  = ho + dy - 1;
            const int xc = pxg + px + dxk - 1;
            const bool ok = ((unsigned)y < 64u) && ((unsigned)xc < 64u);
            const float* xp = xb + ((size_t)((i & 1) * 32 + kq * 4)) * 4096
                                 + y * 64 + xc;
            float va[4];
#pragma unroll
            for (int j = 0; j < 4; ++j) va[j] = ok ? xp[(size_t)j * 4096] : 0.f;
#pragma unroll
            for (int j = 0; j < 4; ++j)
                colsT[i & 1][px * FCPAD + kq * 4 + j] = (_Float16)va[j];
        };
        auto loadA = [&](int i) -> half8 {
            const int tap = i >> 1;
            const int cin0 = (i & 1) * 32 + q * 8;
            const int co = m * 16 + r;
            half8 v;
#pragma unroll
            for (int j = 0; j < 8; ++j)
                v[j] = (co < KOFF) ? (_Float16)w_off[co * 576 + (cin0 + j) * 9 + tap]
                                   : (_Float16)0.f;
            return v;
        };
        stageA(0);
        __syncthreads();
#pragma unroll
        for (int i = 0; i < 18; ++i) {
            if (i < 17) stageA(i + 1);
            half8 a = loadA(i);
            half8 bfr = *(const half8*)&colsT[i & 1][(n * 16 + r) * FCPAD + q * 8];
            am = __builtin_amdgcn_mfma_f32_16x16x32_f16(a, bfr, am, 0, 0, 0);
            __syncthreads();
        }
#pragma unroll
        for (int reg = 0; reg < 4; ++reg) {
            int co = m * 16 + q * 4 + reg;
            if (co < KOFF)
                offlds[co * 32 + (n * 16 + r)] = am[reg] + b_off[co];
        }
    }
    __syncthreads();

    unsigned rmeta[9], rw0[9], rw1[9];
#pragma unroll
    for (int tap = 0; tap < 9; ++tap) {
        float offy = offlds[(2 * tap) * 32 + px];
        float offx = offlds[(2 * tap + 1) * 32 + px];
        float py  = offy + (float)(tap / 3) + (float)(ho - 1);
        float pxf = offx + (float)(tap % 3) + (float)(pxg + px - 1);
        float fy = floorf(py), fx = floorf(pxf);
        int y0 = (int)fy, x0 = (int)fx;
        float wy1 = py - fy, wx1 = pxf - fx;
        float wy0 = 1.f - wy1, wx0 = 1.f - wx1;
        bool y0ok = ((unsigned)y0 < 64u);
        bool x0ok = ((unsigned)x0 < 64u);
        bool y1ok = ((unsigned)(y0 + 1) < 64u);
        bool x1ok = ((unsigned)(x0 + 1) < 64u);
        float w00 = (y0ok && x0ok) ? wy0 * wx0 : 0.f;
        float w01 = (y0ok && x1ok) ? wy0 * wx1 : 0.f;
        float w10 = (y1ok && x0ok) ? wy1 * wx0 : 0.f;
        float w11 = (y1ok && x1ok) ? wy1 * wx1 : 0.f;
        int yc0 = min(max(y0, 0), 63);
        int xc0 = min(max(x0, 0), 63);
        int yc1 = min(max(y0 + 1, 0), 63);
        int xc1 = min(max(x0 + 1, 0), 63);
        union { __half2 h; unsigned u; } c0, c1;
        c0.h = __floats2half2_rn(w00, w01);
        c1.h = __floats2half2_rn(w10, w11);
        rmeta[tap] = (unsigned)(yc0 * 64 + xc0)
                   | ((unsigned)(xc1 - xc0) << 12)
                   | ((unsigned)(yc1 - yc0) << 13);
        rw0[tap] = c0.u;
        rw1[tap] = c1.u;
    }

    floatx4 acc0 = {0.f, 0.f, 0.f, 0.f};
    floatx4 acc1 = {0.f, 0.f, 0.f, 0.f};

    auto gather = [&](int i) {
        const int tap = i >> 1;
        const unsigned m = rmeta[tap];
        const unsigned a00 = (m & 0xfffu) << 2;
        const unsigned a01 = a00 + ((m >> 10) & 4u);
        const unsigned a10 = a00 + ((m >> 5) & 256u);
        const unsigned a11 = a10 + ((m >> 10) & 4u);
        const char* base = (const char*)xb
                         + ((size_t)((i & 1) * 32 + kq * 4)) * 16384;
        float v00[4], v01[4], v10[4], v11[4];
#pragma unroll
        for (int j = 0; j < 4; ++j) {
            const char* xp = base + (size_t)j * 16384;
            v00[j] = *(const float*)(xp + a00);
            v01[j] = *(const float*)(xp + a01);
            v10[j] = *(const float*)(xp + a10);
            v11[j] = *(const float*)(xp + a11);
        }
        union { unsigned u; __half2 h; } c0, c1;
        c0.u = rw0[tap]; c1.u = rw1[tap];
        const float wA = __half2float(c0.h.x), wB = __half2float(c0.h.y);
        const float wC = __half2float(c1.h.x), wD = __half2float(c1.h.y);
#pragma unroll
        for (int j = 0; j < 4; ++j)
            colsT[i & 1][px * FCPAD + kq * 4 + j] =
                (_Float16)(v00[j] * wA + v01[j] * wB + v10[j] * wC + v11[j] * wD);
    };

    auto load_af = [&](int i) -> half8 {
        const int tap = i >> 1;
        const int cin0 = (i & 1) * 32 + q * 8;
        half8 v;
#pragma unroll
        for (int j = 0; j < 8; ++j)
            v[j] = (_Float16)w_dcn[(wid * 16 + r) * 576 + (cin0 + j) * 9 + tap];
        return v;
    };

    gather(0);
    __syncthreads();
#pragma unroll
    for (int i = 0; i < 18; ++i) {
        if (i < 17) gather(i + 1);
        half8 af = load_af(i);
        half8 b0 = *(const half8*)&colsT[i & 1][r * FCPAD + q * 8];
        half8 b1 = *(const half8*)&colsT[i & 1][(16 + r) * FCPAD + q * 8];
        acc0 = __builtin_amdgcn_mfma_f32_16x16x32_f16(af, b0, acc0, 0, 0, 0);
        acc1 = __builtin_amdgcn_mfma_f32_16x16x32_f16(af, b1, acc1, 0, 0, 0);
        if (i < 17) __syncthreads();
    }

#pragma unroll
    for (int reg = 0; reg < 4; ++reg) {
        int co = wid * 16 + q * 4 + reg;
        float bias = b_dcn[co];
        size_t o = (((size_t)b * 64 + co) * 64 + ho) * 64 + pxg;
        out[o + r]      = acc0[reg] + bias;
        out[o + 16 + r] = acc1[reg] + bias;
    }
}

// ---------------------------------------------------------------------------
extern "C" void kernel_launch(void* const* d_in, const int* in_sizes, int n_in,
                              void* d_out, int out_size, void* d_ws, size_t ws_size,
                              hipStream_t stream) {
    const float* x     = (const float*)d_in[0];
    const float* w_off = (const float*)d_in[1];
    const float* b_off = (const float*)d_in[2];
    const float* w_dcn = (const float*)d_in[3];
    const float* b_dcn = (const float*)d_in[4];
    float* out = (float*)d_out;

    char* ws = (char*)d_ws;
    _Float16* w2t    = (_Float16*)ws;
    _Float16* woff2t = (_Float16*)(ws + WOFF2T_OFF);
    _Float16* xh     = (_Float16*)(ws + X_OFF);

    if (ws_size >= (size_t)WS_NEED) {
        prep<<<1240, 256, 0, stream>>>(x, w_dcn, w_off, w2t, woff2t, xh);
        dcn_one<<<2048, 256, 0, stream>>>(xh, w2t, woff2t, b_off, b_dcn, out);
    } else {
        dcn_fb<<<2048, 256, 0, stream>>>(x, w_dcn, w_off, b_off, b_dcn, out);
    }
}

// Round 5
// 104.612 us; speedup vs baseline: 1.0008x; 1.0008x over previous
//
#include <hip/hip_runtime.h>
#include <hip/hip_fp16.h>

// DeformConv2d: B=16, Cin=64, Cout=64, H=W=64, K=3, stride=1, pad=1, dil=1
// Round 21: register-pressure release on R19/R20's halo structure.
// Evidence: schedule(R17)/barriers(R18)/VALU(R20) all null, traffic(R19) -6us;
// pipe model says ~17-20us but dcn_one ~45us -> suspect VGPR spills at the
// launch_bounds(256,4) 128-reg cap (tally ~120-130 at peak in the unrolled
// gather). This round: (a) launch_bounds(256,3) headroom, (b) unroll 1 on the
// 3-chunk loop (kills cross-chunk live ranges), (c) meta+gw packed in one
// uint4 LDS record (one b128 read per tap). No math change -> bit-identical.

#define KOFF 18
#define HROWS 5
#define HCOLS 37
#define HALO_HALFS (HROWS * HCOLS * 64)   // 11840 halfs = 23680 B
#define CS3 192                            // cols chunk stride (3 taps)

#define W2T_HALFS    (18 * 64 * 32)     // [i][64co][32kl], k' = tap*64+cin
#define WOFF2T_HALFS (18 * 32 * 32)     // [i][32co][32kl]
#define W2T_BYTES    (W2T_HALFS * 2)    // 73728
#define WOFF2T_OFF   W2T_BYTES
#define X_OFF        (W2T_BYTES + WOFF2T_HALFS * 2)   // 110592 (16B aligned)
#define XH_BYTES     (16 * 64 * 64 * 64 * 2)          // 8388608
#define WS_NEED      (X_OFF + XH_BYTES)               // 8499200

typedef _Float16 half8 __attribute__((ext_vector_type(8)));
typedef float floatx4 __attribute__((ext_vector_type(4)));

union H8 { half8 v; __half2 h2[4]; uint4 u; };

// ---------------------------------------------------------------------------
// prep: blocks [0,1024): LDS-tiled transpose of one (b,y) plane (coalesced
// both sides). blocks [1024,1240): weight repack (tap-major f16).
__global__ void prep(const float* __restrict__ x,
                     const float* __restrict__ w_dcn,
                     const float* __restrict__ w_off,
                     _Float16* __restrict__ w2t,
                     _Float16* __restrict__ woff2t,
                     _Float16* __restrict__ xh) {
    const int bi = blockIdx.x;
    const int t  = threadIdx.x;
    if (bi < 1024) {
        const int b = bi >> 6, y = bi & 63;
        __shared__ __align__(16) _Float16 tile[64 * 72];
        const int xx = t & 63;
        const int c4 = t >> 6;
        const float* xp = x + (((size_t)b * 64) * 64 + y) * 64;
#pragma unroll
        for (int p = 0; p < 16; ++p) {
            int cin = p * 4 + c4;
            tile[xx * 72 + cin] = (_Float16)xp[(size_t)cin * 4096 + xx];
        }
        __syncthreads();
        const int oct = t & 7;
        const int xl  = t >> 3;
        _Float16* op = xh + ((((size_t)b * 64 + y) * 64) << 6);
#pragma unroll
        for (int p = 0; p < 2; ++p) {
            int xr = p * 32 + xl;
            half8 v = *(const half8*)&tile[xr * 72 + oct * 8];
            *(half8*)&op[(size_t)xr * 64 + oct * 8] = v;
        }
    } else {
        int e = (bi - 1024) * 256 + t;
        if (e < W2T_HALFS) {
            int kl = e & 31, co = (e >> 5) & 63, i = e >> 11;
            int tap = i >> 1, cin = (i & 1) * 32 + kl;
            w2t[e] = (_Float16)w_dcn[co * 576 + cin * 9 + tap];
        } else {
            int e2 = e - W2T_HALFS;
            int kl = e2 & 31, co = (e2 >> 5) & 31, i = e2 >> 10;
            int tap = i >> 1, cin = (i & 1) * 32 + kl;
            woff2t[e2] = (co < KOFF) ? (_Float16)w_off[co * 576 + cin * 9 + tap]
                                     : (_Float16)0.f;
        }
    }
}

// ---------------------------------------------------------------------------
// dcn_one: halo-staged offset conv + geometry + gather + GEMM in one kernel.
__launch_bounds__(256, 3)
__global__ void dcn_one(const _Float16* __restrict__ xh,
                        const _Float16* __restrict__ w2t,
                        const _Float16* __restrict__ woff2t,
                        const float* __restrict__ b_off,
                        const float* __restrict__ b_dcn,
                        float* __restrict__ out) {
    const int bid = blockIdx.x;                 // 0..2047
    const int s   = bid >> 3;
    const int b   = ((bid & 7) << 1) | (s >> 7);
    const int ho  = (s >> 1) & 63;
    const int hlf = s & 1;
    const int t    = threadIdx.x;
    const int lane = t & 63;
    const int wid  = __builtin_amdgcn_readfirstlane(t >> 6);
    const int r    = lane & 15;
    const int q    = lane >> 4;
    const int gpx  = t >> 3;                    // 0..31 gather pixel
    const int oct  = t & 7;                     // 8-cin octet
    const int pxg  = hlf * 32;

    // LDS: halo 23680 + cols 12288 + gpack 4608 = 40576 B -> 4 blocks/CU
    __shared__ __align__(16) _Float16 haloL[HALO_HALFS];
    __shared__ __align__(16) _Float16 colsL[32 * CS3];
    __shared__ __align__(16) uint4    gpackL[288];
    float* offlds = (float*)colsL;              // overlay: used before cols

    const _Float16* xb = xh + ((size_t)b << 18);
    const char* xpb = (const char*)xb;

    // ---- 1. stage halo: rows ho-2..ho+2, cols pxg-2..pxg+34, swizzled ----
    // 16B slot s at (hy,hx) holds cin-octet (s ^ (hx&7)); OOB zero-filled.
    // Incremental (hy,hx) indexing: no div/mod in the loop.
    {
        const int sl = t & 7;
        int rest = t >> 3;                      // hy*37 + hx
        int hx = rest;                          // rest<=31 < 37 -> hy=0
        int hy = 0;
#pragma unroll
        for (int it = 0; it < 6; ++it) {
            if (rest < HROWS * HCOLS) {
                int y  = ho - 2 + hy;
                int xx = pxg - 2 + hx;
                half8 v = {};
                if (((unsigned)y < 64u) && ((unsigned)xx < 64u)) {
                    int oc = sl ^ (hx & 7);
                    v = *(const half8*)&xb[(((size_t)(y * 64 + xx)) << 6) + oc * 8];
                }
                *(half8*)&haloL[(size_t)(rest * 8 + sl) * 8] = v;
            }
            rest += 32;
            hx += 32;
            if (hx >= HCOLS) { hx -= HCOLS; hy += 1; }
        }
    }
    __syncthreads();

    // ---- 2. phase A: offset conv, B-frags straight from halo -------------
    {
        floatx4 am = {0.f, 0.f, 0.f, 0.f};
        const int m = wid & 1, n = wid >> 1;
        const int px_ = n * 16 + r;
        const int wbase = (m * 16 + r) * 32 + q * 8;
#pragma unroll
        for (int tap = 0; tap < 9; ++tap) {
            const int hy  = tap / 3 + 1;                // compile-time (unrolled)
            const int hxA = px_ + (tap % 3) + 1;
            const int sl0 = q ^ (hxA & 7);
            const int bidx = ((hy * HCOLS + hxA) * 8 + sl0) * 8;
            half8 bf0 = *(const half8*)&haloL[bidx];
            half8 a0  = *(const half8*)&woff2t[(2 * tap) * 1024 + wbase];
            am = __builtin_amdgcn_mfma_f32_16x16x32_f16(a0, bf0, am, 0, 0, 0);
            half8 bf1 = *(const half8*)&haloL[bidx ^ 32];   // slot ^4 == byte ^64
            half8 a1  = *(const half8*)&woff2t[(2 * tap + 1) * 1024 + wbase];
            am = __builtin_amdgcn_mfma_f32_16x16x32_f16(a1, bf1, am, 0, 0, 0);
        }
#pragma unroll
        for (int reg = 0; reg < 4; ++reg) {
            int co = m * 16 + q * 4 + reg;
            if (co < KOFF)
                offlds[co * 32 + n * 16 + r] = am[reg] + b_off[co];
        }
    }
    __syncthreads();

    // ---- 3. geometry records (identical weight arithmetic) ---------------
    for (int e = t; e < 9 * 32; e += 256) {
        int tap = e >> 5, px = e & 31;
        float offy = offlds[(2 * tap) * 32 + px];
        float offx = offlds[(2 * tap + 1) * 32 + px];
        float py  = offy + (float)(tap / 3) + (float)(ho - 1);
        float pxf = offx + (float)(tap % 3) + (float)(pxg + px - 1);
        float fy = floorf(py), fx = floorf(pxf);
        int y0 = (int)fy, x0 = (int)fx;
        float wy1 = py - fy, wx1 = pxf - fx;
        float wy0 = 1.f - wy1, wx0 = 1.f - wx1;
        bool y0ok = ((unsigned)y0 < 64u);
        bool x0ok = ((unsigned)x0 < 64u);
        bool y1ok = ((unsigned)(y0 + 1) < 64u);
        bool x1ok = ((unsigned)(x0 + 1) < 64u);
        float w00 = (y0ok && x0ok) ? wy0 * wx0 : 0.f;
        float w01 = (y0ok && x1ok) ? wy0 * wx1 : 0.f;
        float w10 = (y1ok && x0ok) ? wy1 * wx0 : 0.f;
        float w11 = (y1ok && x1ok) ? wy1 * wx1 : 0.f;
        int yc0 = min(max(y0, 0), 63);
        int xc0 = min(max(x0, 0), 63);
        int yc1 = min(max(y0 + 1, 0), 63);
        int xc1 = min(max(x0 + 1, 0), 63);
        union { __half2 h; unsigned u; } c0, c1;
        c0.h = __floats2half2_rn(w00, w01);
        c1.h = __floats2half2_rn(w10, w11);
        // fast path iff all (clamped) corners live inside the staged halo box
        bool fast = (yc0 >= ho - 2) && (yc1 <= ho + 2)
                 && (xc0 >= pxg - 2) && (xc1 <= pxg + 34);
        unsigned meta;
        if (fast) {
            unsigned hy0 = (unsigned)(yc0 - (ho - 2));
            unsigned hx0 = (unsigned)(xc0 - (pxg - 2));
            meta = 0x80000000u | hx0 | (hy0 << 8)
                 | ((unsigned)(xc1 - xc0) << 16)
                 | ((unsigned)(yc1 - yc0) << 17);
        } else {
            meta = (unsigned)(yc0 * 64 + xc0)
                 | ((unsigned)(xc1 - xc0) << 12)
                 | ((unsigned)(yc1 - yc0) << 13);
        }
        uint4 rec;
        rec.x = meta;
        rec.y = c0.u;
        rec.z = c1.u;
        rec.w = 0u;
        gpackL[e] = rec;
    }
    __syncthreads();

    // ---- 4. phase B: 3 chunks of 3 taps; gather from halo LDS ------------
    floatx4 acc0 = {0.f, 0.f, 0.f, 0.f};
    floatx4 acc1 = {0.f, 0.f, 0.f, 0.f};

    // hoisted LDS index bases (halfs)
    const int colsWidx = gpx * CS3 + (oct ^ (gpx & 7)) * 8;     // gather write
    const int rdA = r * CS3 + (q ^ (r & 7)) * 8;                // MFMA b0 read
    const int rdB = (16 + r) * CS3 + (q ^ (r & 7)) * 8;         // MFMA b1 read
    const int wb2 = (wid * 16 + r) * 32 + q * 8;                // w2t lane base

#pragma unroll 1
    for (int c = 0; c < 3; ++c) {
        // weight prefetch first: in flight across the whole gather phase
        half8 wf6[6];
#pragma unroll
        for (int u = 0; u < 6; ++u)
            wf6[u] = *(const half8*)&w2t[(size_t)(c * 6 + u) * 2048 + wb2];

        // gather + combine 3 taps for pixel gpx, octet oct
#pragma unroll
        for (int u3 = 0; u3 < 3; ++u3) {
            const int tap = c * 3 + u3;
            uint4 gp = gpackL[tap * 32 + gpx];
            const unsigned meta = gp.x;
            H8 v00, v01, v10, v11;
            if (meta & 0x80000000u) {
                int hx0 = (int)(meta & 63u);
                int hy0 = (int)((meta >> 8) & 7u);
                int dx  = (int)((meta >> 16) & 1u);
                int dy  = (int)((meta >> 17) & 1u);
                int b0i = hy0 * HCOLS + hx0;
                int s0  = oct ^ (hx0 & 7);
                int s1  = oct ^ ((hx0 + dx) & 7);
                v00.v = *(const half8*)&haloL[(b0i * 8 + s0) * 8];
                v01.v = *(const half8*)&haloL[((b0i + dx) * 8 + s1) * 8];
                v10.v = *(const half8*)&haloL[((b0i + dy * HCOLS) * 8 + s0) * 8];
                v11.v = *(const half8*)&haloL[((b0i + dy * HCOLS + dx) * 8 + s1) * 8];
            } else {
                unsigned a00 = (meta & 0xfffu) * 128u + (unsigned)oct * 16u;
                unsigned dx128  = ((meta >> 12) & 1u) * 128u;
                unsigned dy8192 = ((meta >> 13) & 1u) * 8192u;
                v00.v = *(const half8*)(xpb + a00);
                v01.v = *(const half8*)(xpb + a00 + dx128);
                v10.v = *(const half8*)(xpb + a00 + dy8192);
                v11.v = *(const half8*)(xpb + a00 + dy8192 + dx128);
            }
            union { unsigned u; __half2 h; } cy, cz;
            cy.u = gp.y;
            cz.u = gp.z;
            __half2 W00 = __half2half2(__low2half(cy.h));
            __half2 W01 = __half2half2(__high2half(cy.h));
            __half2 W10 = __half2half2(__low2half(cz.h));
            __half2 W11 = __half2half2(__high2half(cz.h));
            H8 res;
#pragma unroll
            for (int cc = 0; cc < 4; ++cc) {
                __half2 aa = __hmul2(v00.h2[cc], W00);
                aa = __hfma2(v01.h2[cc], W01, aa);
                aa = __hfma2(v10.h2[cc], W10, aa);
                aa = __hfma2(v11.h2[cc], W11, aa);
                res.h2[cc] = aa;
            }
            *(half8*)&colsL[colsWidx + u3 * 64] = res.v;
        }
        __syncthreads();
#pragma unroll
        for (int u = 0; u < 6; ++u) {
            const int u3 = u >> 1;
            const int x32 = (u & 1) * 32;              // ch=1: slot^4 == idx^32
            half8 b0 = *(const half8*)&colsL[(rdA + u3 * 64) ^ x32];
            half8 b1 = *(const half8*)&colsL[(rdB + u3 * 64) ^ x32];
            acc0 = __builtin_amdgcn_mfma_f32_16x16x32_f16(wf6[u], b0, acc0, 0, 0, 0);
            acc1 = __builtin_amdgcn_mfma_f32_16x16x32_f16(wf6[u], b1, acc1, 0, 0, 0);
        }
        if (c < 2) __syncthreads();
    }

    // ---- epilogue --------------------------------------------------------
#pragma unroll
    for (int reg = 0; reg < 4; ++reg) {
        int co = wid * 16 + q * 4 + reg;
        float bias = b_dcn[co];
        size_t o = (((size_t)b * 64 + co) * 64 + ho) * 64 + pxg;
        out[o + r]      = acc0[reg] + bias;
        out[o + 16 + r] = acc1[reg] + bias;
    }
}

// ---------------------------------------------------------------------------
// Fallback (R11-proven, x f32 direct) used only if ws too small.
#define FCPAD 40
__launch_bounds__(256, 4)
__global__ void dcn_fb(const float* __restrict__ x,
                       const float* __restrict__ w_dcn,
                       const float* __restrict__ w_off,
                       const float* __restrict__ b_off,
                       const float* __restrict__ b_dcn,
                       float* __restrict__ out) {
    const int bid = blockIdx.x;
    const int s   = bid >> 3;
    const int b   = ((bid & 7) << 1) | (s >> 7);
    const int ho  = (s >> 1) & 63;
    const int hlf = s & 1;
    const int t    = threadIdx.x;
    const int lane = t & 63;
    const int wid  = __builtin_amdgcn_readfirstlane(t >> 6);
    const int r    = lane & 15;
    const int q    = lane >> 4;
    const int px   = t & 31;
    const int kq   = t >> 5;

    __shared__ __align__(16) _Float16 colsT[2][32 * FCPAD];
    __shared__ __align__(16) float    offlds[KOFF * 32];

    const float* xb = x + (size_t)b * 64 * 4096;
    const int pxg = hlf * 32;

    {
        floatx4 am = {0.f, 0.f, 0.f, 0.f};
        const int m = wid & 1, n = wid >> 1;
        auto stageA = [&](int i) {
            const int tap = i >> 1;
            const int dy = tap / 3, dxk = tap - dy * 3;
            const int y  = ho + dy - 1;
            const int xc = pxg + px + dxk - 1;
            const bool ok = ((unsigned)y < 64u) && ((unsigned)xc < 64u);
            const float* xp = xb + ((size_t)((i & 1) * 32 + kq * 4)) * 4096
                                 + y * 64 + xc;
            float va[4];
#pragma unroll
            for (int j = 0; j < 4; ++j) va[j] = ok ? xp[(size_t)j * 4096] : 0.f;
#pragma unroll
            for (int j = 0; j < 4; ++j)
                colsT[i & 1][px * FCPAD + kq * 4 + j] = (_Float16)va[j];
        };
        auto loadA = [&](int i) -> half8 {
            const int tap = i >> 1;
            const int cin0 = (i & 1) * 32 + q * 8;
            const int co = m * 16 + r;
            half8 v;
#pragma unroll
            for (int j = 0; j < 8; ++j)
                v[j] = (co < KOFF) ? (_Float16)w_off[co * 576 + (cin0 + j) * 9 + tap]
                                   : (_Float16)0.f;
            return v;
        };
        stageA(0);
        __syncthreads();
#pragma unroll
        for (int i = 0; i < 18; ++i) {
            if (i < 17) stageA(i + 1);
            half8 a = loadA(i);
            half8 bfr = *(const half8*)&colsT[i & 1][(n * 16 + r) * FCPAD + q * 8];
            am = __builtin_amdgcn_mfma_f32_16x16x32_f16(a, bfr, am, 0, 0, 0);
            __syncthreads();
        }
#pragma unroll
        for (int reg = 0; reg < 4; ++reg) {
            int co = m * 16 + q * 4 + reg;
            if (co < KOFF)
                offlds[co * 32 + (n * 16 + r)] = am[reg] + b_off[co];
        }
    }
    __syncthreads();

    unsigned rmeta[9], rw0[9], rw1[9];
#pragma unroll
    for (int tap = 0; tap < 9; ++tap) {
        float offy = offlds[(2 * tap) * 32 + px];
        float offx = offlds[(2 * tap + 1) * 32 + px];
        float py  = offy + (float)(tap / 3) + (float)(ho - 1);
        float pxf = offx + (float)(tap % 3) + (float)(pxg + px - 1);
        float fy = floorf(py), fx = floorf(pxf);
        int y0 = (int)fy, x0 = (int)fx;
        float wy1 = py - fy, wx1 = pxf - fx;
        float wy0 = 1.f - wy1, wx0 = 1.f - wx1;
        bool y0ok = ((unsigned)y0 < 64u);
        bool x0ok = ((unsigned)x0 < 64u);
        bool y1ok = ((unsigned)(y0 + 1) < 64u);
        bool x1ok = ((unsigned)(x0 + 1) < 64u);
        float w00 = (y0ok && x0ok) ? wy0 * wx0 : 0.f;
        float w01 = (y0ok && x1ok) ? wy0 * wx1 : 0.f;
        float w10 = (y1ok && x0ok) ? wy1 * wx0 : 0.f;
        float w11 = (y1ok && x1ok) ? wy1 * wx1 : 0.f;
        int yc0 = min(max(y0, 0), 63);
        int xc0 = min(max(x0, 0), 63);
        int yc1 = min(max(y0 + 1, 0), 63);
        int xc1 = min(max(x0 + 1, 0), 63);
        union { __half2 h; unsigned u; } c0, c1;
        c0.h = __floats2half2_rn(w00, w01);
        c1.h = __floats2half2_rn(w10, w11);
        rmeta[tap] = (unsigned)(yc0 * 64 + xc0)
                   | ((unsigned)(xc1 - xc0) << 12)
                   | ((unsigned)(yc1 - yc0) << 13);
        rw0[tap] = c0.u;
        rw1[tap] = c1.u;
    }

    floatx4 acc0 = {0.f, 0.f, 0.f, 0.f};
    floatx4 acc1 = {0.f, 0.f, 0.f, 0.f};

    auto gather = [&](int i) {
        const int tap = i >> 1;
        const unsigned m = rmeta[tap];
        const unsigned a00 = (m & 0xfffu) << 2;
        const unsigned a01 = a00 + ((m >> 10) & 4u);
        const unsigned a10 = a00 + ((m >> 5) & 256u);
        const unsigned a11 = a10 + ((m >> 10) & 4u);
        const char* base = (const char*)xb
                         + ((size_t)((i & 1) * 32 + kq * 4)) * 16384;
        float v00[4], v01[4], v10[4], v11[4];
#pragma unroll
        for (int j = 0; j < 4; ++j) {
            const char* xp = base + (size_t)j * 16384;
            v00[j] = *(const float*)(xp + a00);
            v01[j] = *(const float*)(xp + a01);
            v10[j] = *(const float*)(xp + a10);
            v11[j] = *(const float*)(xp + a11);
        }
        union { unsigned u; __half2 h; } c0, c1;
        c0.u = rw0[tap]; c1.u = rw1[tap];
        const float wA = __half2float(c0.h.x), wB = __half2float(c0.h.y);
        const float wC = __half2float(c1.h.x), wD = __half2float(c1.h.y);
#pragma unroll
        for (int j = 0; j < 4; ++j)
            colsT[i & 1][px * FCPAD + kq * 4 + j] =
                (_Float16)(v00[j] * wA + v01[j] * wB + v10[j] * wC + v11[j] * wD);
    };

    auto load_af = [&](int i) -> half8 {
        const int tap = i >> 1;
        const int cin0 = (i & 1) * 32 + q * 8;
        half8 v;
#pragma unroll
        for (int j = 0; j < 8; ++j)
            v[j] = (_Float16)w_dcn[(wid * 16 + r) * 576 + (cin0 + j) * 9 + tap];
        return v;
    };

    gather(0);
    __syncthreads();
#pragma unroll
    for (int i = 0; i < 18; ++i) {
        if (i < 17) gather(i + 1);
        half8 af = load_af(i);
        half8 b0 = *(const half8*)&colsT[i & 1][r * FCPAD + q * 8];
        half8 b1 = *(const half8*)&colsT[i & 1][(16 + r) * FCPAD + q * 8];
        acc0 = __builtin_amdgcn_mfma_f32_16x16x32_f16(af, b0, acc0, 0, 0, 0);
        acc1 = __builtin_amdgcn_mfma_f32_16x16x32_f16(af, b1, acc1, 0, 0, 0);
        if (i < 17) __syncthreads();
    }

#pragma unroll
    for (int reg = 0; reg < 4; ++reg) {
        int co = wid * 16 + q * 4 + reg;
        float bias = b_dcn[co];
        size_t o = (((size_t)b * 64 + co) * 64 + ho) * 64 + pxg;
        out[o + r]      = acc0[reg] + bias;
        out[o + 16 + r] = acc1[reg] + bias;
    }
}

// ---------------------------------------------------------------------------
extern "C" void kernel_launch(void* const* d_in, const int* in_sizes, int n_in,
                              void* d_out, int out_size, void* d_ws, size_t ws_size,
                              hipStream_t stream) {
    const float* x     = (const float*)d_in[0];
    const float* w_off = (const float*)d_in[1];
    const float* b_off = (const float*)d_in[2];
    const float* w_dcn = (const float*)d_in[3];
    const float* b_dcn = (const float*)d_in[4];
    float* out = (float*)d_out;

    char* ws = (char*)d_ws;
    _Float16* w2t    = (_Float16*)ws;
    _Float16* woff2t = (_Float16*)(ws + WOFF2T_OFF);
    _Float16* xh     = (_Float16*)(ws + X_OFF);

    if (ws_size >= (size_t)WS_NEED) {
        prep<<<1240, 256, 0, stream>>>(x, w_dcn, w_off, w2t, woff2t, xh);
        dcn_one<<<2048, 256, 0, stream>>>(xh, w2t, woff2t, b_off, b_dcn, out);
    } else {
        dcn_fb<<<2048, 256, 0, stream>>>(x, w_dcn, w_off, b_off, b_dcn, out);
    }
}